// Round 9
// baseline (1217.245 us; speedup 1.0000x reference)
//
#include <hip/hip_runtime.h>
#include <hip/hip_bf16.h>

#define DEV __device__ __forceinline__

typedef __attribute__((ext_vector_type(8))) __bf16 bfrag;   // 8 bf16 = 4 VGPRs (A/B frag)
typedef __attribute__((ext_vector_type(4))) float  f32x4;   // C/D frag
typedef __attribute__((ext_vector_type(4))) unsigned int u32x4;

DEV f32x4 mfma32(bfrag a, bfrag b, f32x4 c) {
    return __builtin_amdgcn_mfma_f32_16x16x32_bf16(a, b, c, 0, 0, 0);
}

DEV unsigned short to_bf16(float f) {
    union { __bf16 b; unsigned short u; } cv;
    cv.b = (__bf16)f;
    return cv.u;
}

DEV float bf2f(unsigned short u) {
    union { unsigned int i; float f; } cv;
    cv.i = (unsigned int)u << 16;
    return cv.f;
}

#if defined(__has_builtin)
#if __has_builtin(__builtin_amdgcn_cvt_pk_bf16_f32)
#define HAS_PK_BF16 1
#endif
#endif

DEV unsigned int pk2(float a, float b) {
#ifdef HAS_PK_BF16
    auto r = __builtin_amdgcn_cvt_pk_bf16_f32(a, b);
    unsigned int u;
    __builtin_memcpy(&u, &r, 4);
    return u;
#else
    return (unsigned)to_bf16(a) | ((unsigned)to_bf16(b) << 16);
#endif
}

// pack 4 f32 -> 4 bf16 -> one 8B LDS store
DEV void store4(unsigned short* p, float v0, float v1, float v2, float v3) {
    typedef __attribute__((ext_vector_type(2))) unsigned int uint2v;
    uint2v q;
    q[0] = pk2(v0, v1);
    q[1] = pk2(v2, v3);
    *reinterpret_cast<uint2v*>(p) = q;
}

DEV bfrag bf_from(unsigned int a, unsigned int b, unsigned int c, unsigned int d) {
    u32x4 q; q[0] = a; q[1] = b; q[2] = c; q[3] = d;
    bfrag r; __builtin_memcpy(&r, &q, 16); return r;
}

DEV float fastrcp(float x) { float r; asm("v_rcp_f32 %0, %1" : "=v"(r) : "v"(x)); return r; }

// tanh-form gelu via sigmoid: x*sigmoid(1.5957691x + 0.07135481x^3), |err|<~1.5e-3
DEV float gelu(float x) {
    float u = x * fmaf(0.07135481f, x * x, 1.5957691f);
    float e = __expf(-u);
    return x * fastrcp(1.0f + e);
}

namespace cfg {
constexpr size_t OFF_ACC  = 0;                                  // 128 f32 bins
constexpr size_t OFF_WQ   = 512;                                // fused Wqk
constexpr size_t SZ_HEAD  = (size_t)48 * 64 * 64 * 2;           // 393216
constexpr size_t OFF_WK   = OFF_WQ + SZ_HEAD;                   // fused Wvo = Wv_aug @ Whoo^T
constexpr size_t OFF_WV   = OFF_WK + SZ_HEAD;                   // packed V (input to pack_wvo)
constexpr size_t OFF_WHOO = OFF_WV + SZ_HEAD;                   // fused Wh@Wo (input to pack_wvo)
constexpr size_t OFF_F1   = OFF_WHOO + SZ_HEAD;                 // 6*208*64 bf16
constexpr size_t OFF_F2   = OFF_F1 + (size_t)6 * 208 * 64 * 2;  // 6*64*224 bf16
constexpr size_t OFF_MF   = OFF_F2 + (size_t)6 * 64 * 224 * 2;  // fused M1@M2 [64][64]
constexpr size_t OFF_PP   = OFF_MF + 8192;
constexpr size_t OFF_POSB = OFF_PP + 8192;                      // 16*64 f32 (pos + patch bias)
}

// ---------------- prepack kernels ----------------

// Fused Wqk[lh][n=fq][k=fk] = (1/7) * sum_e Wq_aug[fq][e] * Wk_aug[fk][e]
__global__ void pack_qk(const float* __restrict__ wq, const float* __restrict__ bq,
                        const float* __restrict__ wk, const float* __restrict__ bk,
                        char* __restrict__ ws)
{
    int id = blockIdx.x * 256 + threadIdx.x;   // 48*4096 threads
    int lh = id >> 12, pos = id & 4095;
    int n = pos >> 6, k = pos & 63;
    float s = 0.f;
    if (n <= 49 && k <= 49) {
        const float* aq = (n < 49) ? &wq[((size_t)lh * 49 + n) * 49] : &bq[(size_t)lh * 49];
        const float* ak = (k < 49) ? &wk[((size_t)lh * 49 + k) * 49] : &bk[(size_t)lh * 49];
        for (int e2 = 0; e2 < 49; ++e2) s += aq[e2] * ak[e2];
        s *= (1.f / 7.f);
    }
    ((unsigned short*)(ws + cfg::OFF_WQ))[(size_t)lh * 4096 + pos] = to_bf16(s);
}

// V weights packed [out e 64][in f 64], in-slot 49 = bias (consumed by pack_wvo)
__global__ void pack_v(const float* __restrict__ wv, const float* __restrict__ bv,
                       char* __restrict__ ws)
{
    int id = blockIdx.x * 256 + threadIdx.x;   // 48*4096 threads
    int lh = id >> 12, pos = id & 4095;
    int n = pos >> 6, k = pos & 63;
    float v = 0.f;
    if (n < 49) {
        if (k < 49)       v = wv[((size_t)lh * 49 + k) * 49 + n];
        else if (k == 49) v = bv[lh * 49 + n];
    }
    ((unsigned short*)(ws + cfg::OFF_WV))[(size_t)lh * 4096 + pos] = to_bf16(v);
}

// fused Whoo[lh][d out][e in] = sum_o Wh[lh][e][o]*Wo[l][h*49+o][d]; slot e=49 = bh@Wo + bo/8
// fused Mf[d out][e in] = sum_o M1[e][o]*M2[o][d]; slot e=49 = b1@M2 + b2
__global__ void pack_fused(const float* __restrict__ wh, const float* __restrict__ bh,
                           const float* __restrict__ wo, const float* __restrict__ bo,
                           const float* __restrict__ m1, const float* __restrict__ m1b,
                           const float* __restrict__ m2, const float* __restrict__ m2b,
                           char* __restrict__ ws)
{
    int id = blockIdx.x * 256 + threadIdx.x;     // 48*4096 + 4096 threads
    if (id < 48 * 4096) {
        int lh = id >> 12, pos = id & 4095;
        int l = lh >> 3, h = lh & 7;
        int d = pos >> 6, e = pos & 63;
        float s = 0.f;
        if (d < 49) {
            if (e < 49) {
                for (int o = 0; o < 49; ++o)
                    s += wh[((size_t)lh * 49 + e) * 49 + o] * wo[((size_t)l * 392 + h * 49 + o) * 49 + d];
            } else if (e == 49) {
                for (int o = 0; o < 49; ++o)
                    s += bh[lh * 49 + o] * wo[((size_t)l * 392 + h * 49 + o) * 49 + d];
                s += bo[l * 49 + d] * 0.125f;
            }
        }
        ((unsigned short*)(ws + cfg::OFF_WHOO))[(size_t)lh * 4096 + d * 64 + e] = to_bf16(s);
        return;
    }
    id -= 48 * 4096;
    if (id < 4096) {
        int d = id >> 6, e = id & 63;
        float s = 0.f;
        if (d < 49) {
            if (e < 49) {
                for (int o = 0; o < 49; ++o) s += m1[e * 49 + o] * m2[o * 49 + d];
            } else if (e == 49) {
                for (int o = 0; o < 49; ++o) s += m1b[o] * m2[o * 49 + d];
                s += m2b[d];
            }
        }
        ((unsigned short*)(ws + cfg::OFF_MF))[d * 64 + e] = to_bf16(s);
    }
}

// Fused Wvo[lh][d out][f in] = sum_{e<49} Wv_aug[f][e] * Whoo_w[d][e];
// f=49 row += Whoo bias slot (exact: softmax rows sum to 1).
// Rows d>=49 are exact zeros (Whoo pad).
__global__ void pack_wvo(char* __restrict__ ws)
{
    int id = blockIdx.x * 256 + threadIdx.x;   // 48*4096 threads
    int lh = id >> 12, pos = id & 4095;
    int d = pos >> 6, f = pos & 63;
    const unsigned short* WVp = (const unsigned short*)(ws + cfg::OFF_WV) + (size_t)lh * 4096;
    const unsigned short* WH  = (const unsigned short*)(ws + cfg::OFF_WHOO) + (size_t)lh * 4096;
    float s = 0.f;
    for (int e = 0; e < 49; ++e)
        s += bf2f(WVp[e * 64 + f]) * bf2f(WH[d * 64 + e]);
    if (f == 49) s += bf2f(WH[d * 64 + 49]);
    ((unsigned short*)(ws + cfg::OFF_WK))[(size_t)lh * 4096 + d * 64 + f] = to_bf16(s);
}

__global__ void pack_rest(const float* __restrict__ f1w, const float* __restrict__ f1b,
                          const float* __restrict__ f2w, const float* __restrict__ f2b,
                          const float* __restrict__ ppw, const float* __restrict__ ppb,
                          const float* __restrict__ pos, char* __restrict__ ws)
{
    int id = blockIdx.x * 256 + threadIdx.x;
    if (id < 6 * 208 * 64) {                                    // FFN1: [l][n=208][k=64], k-slot49=bias
        int l = id / (208 * 64), rem = id % (208 * 64), n = rem / 64, k = rem % 64;
        float v = 0.f;
        if (n < 196) {
            if (k < 49)       v = f1w[((size_t)l * 49 + k) * 196 + n];
            else if (k == 49) v = f1b[l * 196 + n];
        }
        ((unsigned short*)(ws + cfg::OFF_F1))[id] = to_bf16(v);
        return;
    }
    id -= 6 * 208 * 64;
    if (id < 6 * 64 * 224) {                                    // FFN2: [l][n=64][k=224], k-slot196=bias
        int l = id / (64 * 224), rem = id % (64 * 224), n = rem / 224, k = rem % 224;
        float v = 0.f;
        if (n < 49) {
            if (k < 196)       v = f2w[((size_t)l * 196 + k) * 49 + n];
            else if (k == 196) v = f2b[l * 49 + n];
        }
        ((unsigned short*)(ws + cfg::OFF_F2))[id] = to_bf16(v);
        return;
    }
    id -= 6 * 64 * 224;
    if (id < 4096) {                                            // patch proj [n][k] (bias via POSB)
        int n = id >> 6, k = id & 63;
        ((unsigned short*)(ws + cfg::OFF_PP))[id] = to_bf16((n < 49 && k < 49) ? ppw[k * 49 + n] : 0.f);
        return;
    }
    id -= 4096;
    if (id < 1024) {                                            // posb[p][e] = pos + patch bias
        int p = id >> 6, e = id & 63;
        ((float*)(ws + cfg::OFF_POSB))[id] = (e < 49) ? pos[p * 49 + e] + ppb[e] : 0.f;
        return;
    }
    id -= 1024;
    if (id < 128) ((float*)(ws + cfg::OFF_ACC))[id] = 0.f;      // zero accumulator bins
}

// ---------------- main fused kernel ----------------
// Round 9: 2 waves/WG (2 elems each, r8 dataflow inside the wave) + shared
// DOUBLE-BUFFERED LDS WEIGHT STAGING for the attention head stream.
// Evidence: across r1..r8, time tracks the per-element instruction/latency
// stream and is ~independent of residency (3.7..14.6 waves/CU: <±10%). The
// dominant serial term is ~64 load->use batches/layer in the head loop, each
// exposing full L2 latency (compiler issues weight loads right before use).
// Fix with ZERO VGPR cost (r6's register prefetch failed only via its VGPR
// bill): both waves consume the identical weight stream, so stage head h+1's
// 16KB (wqk+wvo, identity byte layout) into a shared LDS buffer via 16 async
// global_load_lds (8 per wave) issued at the top of head h; one
// __syncthreads() per head is the fence (its implicit vmcnt-drain lands the
// stage; the stage had a full head of compute to fly). Head 0 of layer l+1
// stages during head 7 and is covered by head 7 + FFN. Also halves
// per-element head-weight L2 traffic (one stage serves 4 elements).
// LDS/WG = 18432 (private) + 32768 (staging) = 51200 B -> 3 WGs/CU.

__global__ __launch_bounds__(128, 2)
void vit_main(const float* __restrict__ x, const int* __restrict__ trg,
              const float* __restrict__ cw1, const float* __restrict__ cb1,
              const float* __restrict__ cw2, const float* __restrict__ cb2,
              char* __restrict__ ws)
{
    constexpr int S64 = 72;           // [16][64] tile stride (ushorts), 144B
    constexpr int VC  = 36;           // FFN chunk [16 tok][32+4] stride, 72B
    constexpr int TA = 0, TB = 1152, EL = 2304;
    // per-wave private: 2 elems x EL; shared weight staging: 2 bufs x 8192 ush
    __shared__ unsigned short smb[4 * EL + 16384];   // 51200 B -> 3 WGs/CU

    const int tid  = threadIdx.x;
    const int wid  = tid >> 6;               // which independent wave
    const int lane = tid & 63;
    const int g = lane >> 4, c = lane & 15;
    const long e0 = (long)blockIdx.x * 4 + wid * 2;
    unsigned short* const sm = smb + wid * 2 * EL;   // per-wave private LDS
    unsigned short* const wbuf = smb + 4 * EL;       // shared staging (16384 ush)
    const f32x4 FZ = {0.f, 0.f, 0.f, 0.f};

    // shfl source lanes for the 4-lane D->frag transpose
    const int src0 = ((( 2 * g )     & 3) << 4) | c;
    const int src1 = (((2 * g + 1) & 3) << 4) | c;
    const bool glo = (g < 2);

    const unsigned short* F1 = (const unsigned short*)(ws + cfg::OFF_F1);
    const unsigned short* F2 = (const unsigned short*)(ws + cfg::OFF_F2);
    const unsigned short* MF = (const unsigned short*)(ws + cfg::OFF_MF);
    const unsigned short* PP = (const unsigned short*)(ws + cfg::OFF_PP);
    const float* POSB = (const float*)(ws + cfg::OFF_POSB);
    float* ACC = (float*)(ws + cfg::OFF_ACC);

    // async stage of head lh's weights (wqk 8KB + wvo 8KB, identity layout)
    // into wbuf[buf]; wave wid issues 8 of the 16 1KB global_load_lds.
    const char* const WQKb = (const char*)ws + cfg::OFF_WQ;
    const char* const WVOb = (const char*)ws + cfg::OFF_WK;
    auto stage = [&](int buf, int lh) {
        char* dstb = (char*)wbuf + (buf << 14);
        #pragma unroll
        for (int t = 0; t < 8; ++t) {
            int j = wid * 8 + t;
            const char* src = ((j < 8) ? WQKb + (size_t)lh * 8192 + (j << 10)
                                       : WVOb + (size_t)lh * 8192 + ((j - 8) << 10))
                              + lane * 16;
            __builtin_amdgcn_global_load_lds(
                (const __attribute__((address_space(1))) unsigned int*)src,
                (__attribute__((address_space(3))) unsigned int*)(dstb + (j << 10)),
                16, 0, 0);
        }
    };

    // ---- stage x -> TA ([tok][feat] bf16, feats>=49 zero)
    #pragma unroll
    for (int u = 0; u < 2; ++u) {
        const float* xb = x + (e0 + u) * 784;
        #pragma unroll
        for (int it = 0; it < 8; ++it) {
            int i = it * 64 + lane;
            int p = i >> 5, ee = (i & 31) * 2;
            float v0 = (ee < 49) ? xb[p * 49 + ee] : 0.f;
            float v1 = (ee + 1 < 49) ? xb[p * 49 + ee + 1] : 0.f;
            *reinterpret_cast<unsigned int*>(&sm[u * EL + TA + p * S64 + ee]) = pk2(v0, v1);
        }
    }
    // prefetch layer 0 head 0 weights; barrier lands it (and partner's half)
    stage(0, 0);
    __syncthreads();

    // B-fragment loader from a [16][64] tile (rows = n/tok, cols = k contiguous)
    bfrag a_h[2][2];
    auto loadB = [&](int off, bfrag (&af)[2][2]) {
        #pragma unroll
        for (int u = 0; u < 2; ++u)
            #pragma unroll
            for (int kk = 0; kk < 2; ++kk)
                af[u][kk] = *(const bfrag*)&sm[u * EL + off + c * S64 + kk * 32 + g * 8];
    };
    loadB(TA, a_h);

    // ---- patch proj (transposed) + posb -> hreg  (lane: f=16mt+4g+r, tok=c)
    f32x4 hreg[2][4];
    #pragma unroll
    for (int mt = 0; mt < 4; ++mt) {
        f32x4 t0 = FZ, t1 = FZ;
        #pragma unroll
        for (int kk = 0; kk < 2; ++kk) {
            bfrag w = *(const bfrag*)&PP[(mt * 16 + c) * 64 + kk * 32 + g * 8];
            t0 = mfma32(w, a_h[0][kk], t0);
            t1 = mfma32(w, a_h[1][kk], t1);
        }
        f32x4 pb = *(const f32x4*)&POSB[c * 64 + mt * 16 + 4 * g];
        hreg[0][mt] = t0 + pb;
        hreg[1][mt] = t1 + pb;
    }

    // =================== layer loop ===================
    for (int l = 0; l < 6; ++l) {
        // stage h -> TA, set constant-1 slot at feat 49
        #pragma unroll
        for (int u = 0; u < 2; ++u)
            #pragma unroll
            for (int mt = 0; mt < 4; ++mt)
                store4(&sm[u * EL + TA + c * S64 + mt * 16 + 4 * g],
                       hreg[u][mt][0], hreg[u][mt][1], hreg[u][mt][2], hreg[u][mt][3]);
        if (lane < 32) sm[(lane >> 4) * EL + TA + (lane & 15) * S64 + 49] = 0x3F80;
        loadB(TA, a_h);

        f32x4 oacc[2][4];
        #pragma unroll
        for (int u = 0; u < 2; ++u)
            #pragma unroll
            for (int mt = 0; mt < 4; ++mt) oacc[u][mt] = FZ;

        // ---------- attention heads (LDS-staged weight stream) ----------
        for (int hh = 0; hh < 8; ++hh) {
            const int cur = hh & 1;
            // issue next stage NOW (async, zero VGPR); consumed after barrier
            {
                int nlh = (hh < 7) ? (l * 8 + hh + 1) : ((l < 5) ? (l + 1) * 8 : -1);
                if (nlh >= 0) {
                    stage(cur ^ 1, nlh);
                    __builtin_amdgcn_sched_barrier(0);   // keep the issue early
                }
            }
            const unsigned short* wq_l = wbuf + (cur << 13);       // 8192 ush/buf
            const unsigned short* wv_l = wq_l + 4096;

            // T[k_tok][fq] -> TB (the one remaining LDS round trip per head)
            #pragma unroll
            for (int mt = 0; mt < 4; ++mt) {
                f32x4 t0 = FZ, t1 = FZ;
                #pragma unroll
                for (int kk = 0; kk < 2; ++kk) {
                    bfrag wf = *(const bfrag*)&wq_l[(mt * 16 + c) * 64 + kk * 32 + g * 8];
                    t0 = mfma32(wf, a_h[0][kk], t0);
                    t1 = mfma32(wf, a_h[1][kk], t1);
                }
                store4(&sm[0 * EL + TB + c * S64 + mt * 16 + 4 * g], t0[0], t0[1], t0[2], t0[3]);
                store4(&sm[1 * EL + TB + c * S64 + mt * 16 + 4 * g], t1[0], t1[1], t1[2], t1[3]);
            }

            // S^T = T·h_aug^T, softmax -> P as in-register B-frag (no LDS)
            bfrag bp[2];
            #pragma unroll
            for (int u = 0; u < 2; ++u) {
                f32x4 sc = FZ;
                #pragma unroll
                for (int kk = 0; kk < 2; ++kk) {
                    bfrag akf = *(const bfrag*)&sm[u * EL + TB + c * S64 + kk * 32 + g * 8];
                    sc = mfma32(akf, a_h[u][kk], sc);
                }
                float s0 = sc[0], s1 = sc[1], s2 = sc[2], s3 = sc[3];
                float m = fmaxf(fmaxf(s0, s1), fmaxf(s2, s3));
                m = fmaxf(m, __shfl_xor(m, 16));
                m = fmaxf(m, __shfl_xor(m, 32));
                float p0 = __expf(s0 - m), p1 = __expf(s1 - m);
                float p2 = __expf(s2 - m), p3 = __expf(s3 - m);
                float t = p0 + p1 + p2 + p3;
                t += __shfl_xor(t, 16);
                t += __shfl_xor(t, 32);
                float inv = fastrcp(t);
                // P[q=c][k=4g+r] -> B-frag needs P[q=c][k=8g+j]
                unsigned int pka = pk2(p0 * inv, p1 * inv);
                unsigned int pkb = pk2(p2 * inv, p3 * inv);
                unsigned int b0 = (unsigned)__shfl((int)pka, src0);
                unsigned int b1 = (unsigned)__shfl((int)pkb, src0);
                unsigned int b2 = (unsigned)__shfl((int)pka, src1);
                unsigned int b3 = (unsigned)__shfl((int)pkb, src1);
                bp[u] = bf_from(glo ? b0 : 0u, glo ? b1 : 0u,
                                glo ? b2 : 0u, glo ? b3 : 0u);
            }

            // U = h_aug·Wvo per nt, transpose in-register, PV accumulate
            #pragma unroll
            for (int nt = 0; nt < 4; ++nt) {
                bfrag wvf0 = *(const bfrag*)&wv_l[(nt * 16 + c) * 64 + 0 * 32 + g * 8];
                bfrag wvf1 = *(const bfrag*)&wv_l[(nt * 16 + c) * 64 + 1 * 32 + g * 8];
                #pragma unroll
                for (int u = 0; u < 2; ++u) {
                    f32x4 v = FZ;
                    v = mfma32(a_h[u][0], wvf0, v);
                    v = mfma32(a_h[u][1], wvf1, v);
                    unsigned int va = pk2(v[0], v[1]);
                    unsigned int vb = pk2(v[2], v[3]);
                    unsigned int u0 = (unsigned)__shfl((int)va, src0);
                    unsigned int u1 = (unsigned)__shfl((int)vb, src0);
                    unsigned int u2 = (unsigned)__shfl((int)va, src1);
                    unsigned int u3 = (unsigned)__shfl((int)vb, src1);
                    bfrag uf = bf_from(glo ? u0 : 0u, glo ? u1 : 0u,
                                       glo ? u2 : 0u, glo ? u3 : 0u);
                    oacc[u][nt] = mfma32(uf, bp[u], oacc[u][nt]);
                }
            }

            // fence: my stage landed (implicit vmcnt drain), partner done
            // reading wbuf[cur] -> next head may overwrite it
            __syncthreads();
        } // heads

        // ---------- LN1: y = LN(h + attn_out) -> yreg, store y -> TA (+slot) ----------
        f32x4 yreg[2][4];
        {
            const float* ln1wp = (const float*)(ws + cfg::OFF_POSB + 4096);  // LN tables after POSB
            const float* ln1bp = ln1wp + 384;
            #pragma unroll
            for (int u = 0; u < 2; ++u) {
                float z[4][4];
                float s = 0.f, q2 = 0.f;
                #pragma unroll
                for (int mt = 0; mt < 4; ++mt)
                    #pragma unroll
                    for (int r = 0; r < 4; ++r) {
                        float zz = hreg[u][mt][r] + oacc[u][mt][r];
                        z[mt][r] = zz;
                        s += zz;
                        q2 += zz * zz;
                    }
                s += __shfl_xor(s, 16); s += __shfl_xor(s, 32);
                q2 += __shfl_xor(q2, 16); q2 += __shfl_xor(q2, 32);
                float mu = s * (1.f / 49.f);
                float var = q2 * (1.f / 49.f) - mu * mu;
                float rstd = rsqrtf(var + 1e-5f);
                #pragma unroll
                for (int mt = 0; mt < 4; ++mt) {
                    f32x4 lwv = *(const f32x4*)&ln1wp[l * 64 + mt * 16 + 4 * g];
                    f32x4 lbv = *(const f32x4*)&ln1bp[l * 64 + mt * 16 + 4 * g];
                    #pragma unroll
                    for (int r = 0; r < 4; ++r)
                        yreg[u][mt][r] = (z[mt][r] - mu) * rstd * lwv[r] + lbv[r];
                    store4(&sm[u * EL + TA + c * S64 + mt * 16 + 4 * g],
                           yreg[u][mt][0], yreg[u][mt][1], yreg[u][mt][2], yreg[u][mt][3]);
                }
            }
        }
        if (lane < 32) sm[(lane >> 4) * EL + TA + (lane & 15) * S64 + 49] = 0x3F80;

        // ---------- FFN1 -> FFN2 chunked (32 mid-feats/chunk through TB) ----------
        f32x4 zac[2][4];
        #pragma unroll
        for (int u = 0; u < 2; ++u)
            #pragma unroll
            for (int mt = 0; mt < 4; ++mt) zac[u][mt] = FZ;
        {
            bfrag ay[2][2];
            loadB(TA, ay);
            const unsigned short* F1l = F1 + (size_t)l * 208 * 64;
            const unsigned short* F2l = F2 + (size_t)l * 64 * 224;
            #pragma unroll
            for (int ci = 0; ci < 7; ++ci) {
                #pragma unroll
                for (int t = 0; t < 2; ++t) {
                    const int mtile = ci * 2 + t;
                    if (mtile < 13) {
                        f32x4 m0 = FZ, m1 = FZ;
                        #pragma unroll
                        for (int kk = 0; kk < 2; ++kk) {
                            bfrag wf = *(const bfrag*)&F1l[(mtile * 16 + c) * 64 + kk * 32 + g * 8];
                            m0 = mfma32(wf, ay[0][kk], m0);
                            m1 = mfma32(wf, ay[1][kk], m1);
                        }
                        store4(&sm[0 * EL + TB + c * VC + t * 16 + 4 * g],
                               gelu(m0[0]), gelu(m0[1]), gelu(m0[2]), gelu(m0[3]));
                        store4(&sm[1 * EL + TB + c * VC + t * 16 + 4 * g],
                               gelu(m1[0]), gelu(m1[1]), gelu(m1[2]), gelu(m1[3]));
                    } else {
                        // mtile 13: mid cols 208..223 = zeros (K-pad for FFN2 kk=6)
                        int u2 = lane >> 5, r5 = lane & 31, row = r5 >> 1, half = r5 & 1;
                        *(f32x4*)&sm[u2 * EL + TB + row * VC + 16 + half * 8] = FZ;
                    }
                }
                if (ci == 6) {
                    // constant-1 slot at mid col 196 -> chunk local col 4
                    if (lane < 32) sm[(lane >> 4) * EL + TB + (lane & 15) * VC + 4] = 0x3F80;
                }
                // FFN2 partial accumulate: kk = ci
                #pragma unroll
                for (int u = 0; u < 2; ++u) {
                    bfrag am = *(const bfrag*)&sm[u * EL + TB + c * VC + g * 8];
                    #pragma unroll
                    for (int mt = 0; mt < 4; ++mt) {
                        bfrag wf = *(const bfrag*)&F2l[(mt * 16 + c) * 224 + ci * 32 + g * 8];
                        zac[u][mt] = mfma32(wf, am, zac[u][mt]);
                    }
                }
            }
        }

        // ---------- residual + LN2 -> hreg (hn), store hn -> TA (+slot) ----------
        {
            const float* ln2wp = (const float*)(ws + cfg::OFF_POSB + 4096) + 768;
            const float* ln2bp = ln2wp + 384;
            #pragma unroll
            for (int u = 0; u < 2; ++u) {
                float z[4][4];
                float s = 0.f, q2 = 0.f;
                #pragma unroll
                for (int mt = 0; mt < 4; ++mt)
                    #pragma unroll
                    for (int r = 0; r < 4; ++r) {
                        float zz = yreg[u][mt][r] + zac[u][mt][r];
                        z[mt][r] = zz;
                        s += zz;
                        q2 += zz * zz;
                    }
                s += __shfl_xor(s, 16); s += __shfl_xor(s, 32);
                q2 += __shfl_xor(q2, 16); q2 += __shfl_xor(q2, 32);
                float mu = s * (1.f / 49.f);
                float var = q2 * (1.f / 49.f) - mu * mu;
                float rstd = rsqrtf(var + 1e-5f);
                #pragma unroll
                for (int mt = 0; mt < 4; ++mt) {
                    f32x4 lwv = *(const f32x4*)&ln2wp[l * 64 + mt * 16 + 4 * g];
                    f32x4 lbv = *(const f32x4*)&ln2bp[l * 64 + mt * 16 + 4 * g];
                    #pragma unroll
                    for (int r = 0; r < 4; ++r)
                        hreg[u][mt][r] = (z[mt][r] - mu) * rstd * lwv[r] + lbv[r];
                    store4(&sm[u * EL + TA + c * S64 + mt * 16 + 4 * g],
                           hreg[u][mt][0], hreg[u][mt][1], hreg[u][mt][2], hreg[u][mt][3]);
                }
            }
        }
        if (lane < 32) sm[(lane >> 4) * EL + TA + (lane & 15) * S64 + 49] = 0x3F80;

        // ---------- inter-block MLP (fused M1@M2, bias in slot) ----------
        {
            bfrag an[2][2];
            loadB(TA, an);
            #pragma unroll
            for (int mt = 0; mt < 4; ++mt) {
                f32x4 t0 = FZ, t1 = FZ;
                #pragma unroll
                for (int kk = 0; kk < 2; ++kk) {
                    bfrag wf = *(const bfrag*)&MF[(mt * 16 + c) * 64 + kk * 32 + g * 8];
                    t0 = mfma32(wf, an[0][kk], t0);
                    t1 = mfma32(wf, an[1][kk], t1);
                }
                hreg[0][mt] = t0;
                hreg[1][mt] = t1;
            }
        }
    } // layers

    // =================== pooling + classifier + loss (fp32, per wave) ===================
    float loss_blk = 0.f, corr_blk = 0.f;
    #pragma unroll
    for (int u = 0; u < 2; ++u)
        #pragma unroll
        for (int mt = 0; mt < 4; ++mt)
            store4(&sm[u * EL + TA + c * S64 + mt * 16 + 4 * g],
                   hreg[u][mt][0], hreg[u][mt][1], hreg[u][mt][2], hreg[u][mt][3]);

    for (int u = 0; u < 2; ++u) {
        float s = 0.f;
        #pragma unroll
        for (int p = 0; p < 16; ++p)
            s += (float)(*reinterpret_cast<const __bf16*>(&sm[u * EL + TA + p * S64 + lane]));
        float* pf = reinterpret_cast<float*>(&sm[u * EL + TB]);   // TB dead: f32 scratch
        pf[lane] = s * (1.f / 16.f);
        if (lane < 25) {
            float t = cb1[lane];
            for (int d2 = 0; d2 < 49; ++d2) t += pf[d2] * cw1[d2 * 25 + lane];
            pf[64 + lane] = t;
        }
        if (lane < 10) {
            float t2 = cb2[lane];
            for (int k2 = 0; k2 < 25; ++k2) t2 += pf[64 + k2] * cw2[k2 * 10 + lane];
            pf[96 + lane] = t2;
        }
        if (lane == 0) {
            float m = pf[96]; int am_ = 0;
            for (int j = 1; j < 10; ++j) if (pf[96 + j] > m) { m = pf[96 + j]; am_ = j; }
            float se = 0.f;
            for (int j = 0; j < 10; ++j) se += __expf(pf[96 + j] - m);
            float logZ = m + logf(se);
            int t = trg[e0 + u];
            loss_blk += logZ - pf[96 + t];
            corr_blk += (am_ == t) ? 1.f : 0.f;
        }
    }
    if (lane == 0) {
        int bin = (int)((blockIdx.x * 2 + wid) & 63);
        atomicAdd(&ACC[bin * 2 + 0], loss_blk);
        atomicAdd(&ACC[bin * 2 + 1], corr_blk);
    }
}

// pack LN params [6][64] x4 (w1,b1,w2,b2) after POSB
__global__ void pack_ln(const float* __restrict__ ln1w, const float* __restrict__ ln1b,
                        const float* __restrict__ ln2w, const float* __restrict__ ln2b,
                        char* __restrict__ ws)
{
    int id = blockIdx.x * 256 + threadIdx.x;     // 1536 threads
    if (id >= 1536) return;
    int which = id / 384, r = id % 384, l = r >> 6, f = r & 63;
    const float* s = (which == 0) ? ln1w : (which == 1) ? ln1b : (which == 2) ? ln2w : ln2b;
    float v = (f < 49) ? s[l * 49 + f] : 0.f;
    ((float*)(ws + cfg::OFF_POSB + 4096))[which * 384 + r] = v;
}

__global__ void finalize_k(const char* __restrict__ ws, float* __restrict__ out)
{
    const float* ACC = (const float*)(ws + cfg::OFF_ACC);
    int lane = threadIdx.x;
    float a = ACC[lane * 2 + 0];
    float b = ACC[lane * 2 + 1];
    for (int m = 1; m < 64; m <<= 1) {
        a += __shfl_xor(a, m);
        b += __shfl_xor(b, m);
    }
    if (lane == 0) {
        out[0] = a * (1.f / 16384.f);
        out[1] = b * (1.f / 16384.f);
    }
}

// ---------------- host launcher ----------------

extern "C" void kernel_launch(void* const* d_in, const int* in_sizes, int n_in,
                              void* d_out, int out_size, void* d_ws, size_t ws_size,
                              hipStream_t stream)
{
    const float* x    = (const float*)d_in[0];
    const int*   trg  = (const int*)  d_in[1];
    const float* ppw  = (const float*)d_in[2];
    const float* ppb  = (const float*)d_in[3];
    const float* pos  = (const float*)d_in[4];
    const float* wq   = (const float*)d_in[5];
    const float* bq   = (const float*)d_in[6];
    const float* wk   = (const float*)d_in[7];
    const float* bk   = (const float*)d_in[8];
    const float* wv   = (const float*)d_in[9];
    const float* bv   = (const float*)d_in[10];
    const float* wh   = (const float*)d_in[11];
    const float* bh   = (const float*)d_in[12];
    const float* wo   = (const float*)d_in[13];
    const float* bo   = (const float*)d_in[14];
    const float* ln1w = (const float*)d_in[15];
    const float* ln1b = (const float*)d_in[16];
    const float* ln2w = (const float*)d_in[17];
    const float* ln2b = (const float*)d_in[18];
    const float* f1w  = (const float*)d_in[19];
    const float* f1b  = (const float*)d_in[20];
    const float* f2w  = (const float*)d_in[21];
    const float* f2b  = (const float*)d_in[22];
    const float* m1w  = (const float*)d_in[23];
    const float* m1b  = (const float*)d_in[24];
    const float* m2w  = (const float*)d_in[25];
    const float* m2b  = (const float*)d_in[26];
    const float* cw1  = (const float*)d_in[27];
    const float* cb1  = (const float*)d_in[28];
    const float* cw2  = (const float*)d_in[29];
    const float* cb2  = (const float*)d_in[30];
    char* ws = (char*)d_ws;

    pack_qk<<<768, 256, 0, stream>>>(wq, bq, wk, bk, ws);
    pack_v<<<768, 256, 0, stream>>>(wv, bv, ws);
    pack_fused<<<784, 256, 0, stream>>>(wh, bh, wo, bo, m1w, m1b, m2w, m2b, ws);
    pack_wvo<<<768, 256, 0, stream>>>(ws);
    pack_rest<<<669, 256, 0, stream>>>(f1w, f1b, f2w, f2b, ppw, ppb, pos, ws);
    pack_ln<<<6, 256, 0, stream>>>(ln1w, ln1b, ln2w, ln2b, ws);
    vit_main<<<16384 / 4, 128, 0, stream>>>(x, trg, cw1, cb1, cw2, cb2, ws);
    finalize_k<<<1, 64, 0, stream>>>(ws, (float*)d_out);
}

// Round 10
// 1181.755 us; speedup vs baseline: 1.0300x; 1.0300x over previous
//
#include <hip/hip_runtime.h>
#include <hip/hip_bf16.h>

#define DEV __device__ __forceinline__

typedef __attribute__((ext_vector_type(8))) __bf16 bfrag;   // 8 bf16 = 4 VGPRs (A/B frag)
typedef __attribute__((ext_vector_type(4))) float  f32x4;   // C/D frag
typedef __attribute__((ext_vector_type(4))) unsigned int u32x4;

DEV f32x4 mfma32(bfrag a, bfrag b, f32x4 c) {
    return __builtin_amdgcn_mfma_f32_16x16x32_bf16(a, b, c, 0, 0, 0);
}

DEV unsigned short to_bf16(float f) {
    union { __bf16 b; unsigned short u; } cv;
    cv.b = (__bf16)f;
    return cv.u;
}

DEV float bf2f(unsigned short u) {
    union { unsigned int i; float f; } cv;
    cv.i = (unsigned int)u << 16;
    return cv.f;
}

#if defined(__has_builtin)
#if __has_builtin(__builtin_amdgcn_cvt_pk_bf16_f32)
#define HAS_PK_BF16 1
#endif
#endif

DEV unsigned int pk2(float a, float b) {
#ifdef HAS_PK_BF16
    auto r = __builtin_amdgcn_cvt_pk_bf16_f32(a, b);
    unsigned int u;
    __builtin_memcpy(&u, &r, 4);
    return u;
#else
    return (unsigned)to_bf16(a) | ((unsigned)to_bf16(b) << 16);
#endif
}

// pack 4 f32 -> 4 bf16 -> one 8B LDS store
DEV void store4(unsigned short* p, float v0, float v1, float v2, float v3) {
    typedef __attribute__((ext_vector_type(2))) unsigned int uint2v;
    uint2v q;
    q[0] = pk2(v0, v1);
    q[1] = pk2(v2, v3);
    *reinterpret_cast<uint2v*>(p) = q;
}

DEV bfrag bf_from(unsigned int a, unsigned int b, unsigned int c, unsigned int d) {
    u32x4 q; q[0] = a; q[1] = b; q[2] = c; q[3] = d;
    bfrag r; __builtin_memcpy(&r, &q, 16); return r;
}

DEV float fastrcp(float x) { float r; asm("v_rcp_f32 %0, %1" : "=v"(r) : "v"(x)); return r; }

// tanh-form gelu via sigmoid: x*sigmoid(1.5957691x + 0.07135481x^3), |err|<~1.5e-3
DEV float gelu(float x) {
    float u = x * fmaf(0.07135481f, x * x, 1.5957691f);
    float e = __expf(-u);
    return x * fastrcp(1.0f + e);
}

namespace cfg {
constexpr size_t OFF_ACC  = 0;                                  // 128 f32 bins
constexpr size_t OFF_WQ   = 512;                                // fused Wqk
constexpr size_t SZ_HEAD  = (size_t)48 * 64 * 64 * 2;           // 393216
constexpr size_t OFF_WK   = OFF_WQ + SZ_HEAD;                   // fused Wvo = Wv_aug @ Whoo^T
constexpr size_t OFF_WV   = OFF_WK + SZ_HEAD;                   // packed V (input to pack_wvo)
constexpr size_t OFF_WHOO = OFF_WV + SZ_HEAD;                   // fused Wh@Wo (input to pack_wvo)
constexpr size_t OFF_F1   = OFF_WHOO + SZ_HEAD;                 // 6*208*64 bf16
constexpr size_t OFF_F2   = OFF_F1 + (size_t)6 * 208 * 64 * 2;  // 6*64*224 bf16
constexpr size_t OFF_MF   = OFF_F2 + (size_t)6 * 64 * 224 * 2;  // fused M1@M2 [64][64]
constexpr size_t OFF_PP   = OFF_MF + 8192;
constexpr size_t OFF_POSB = OFF_PP + 8192;                      // 16*64 f32 (pos + patch bias)
}

// ---------------- prepack kernels ----------------

// Fused Wqk[lh][n=fq][k=fk] = (1/7) * sum_e Wq_aug[fq][e] * Wk_aug[fk][e]
__global__ void pack_qk(const float* __restrict__ wq, const float* __restrict__ bq,
                        const float* __restrict__ wk, const float* __restrict__ bk,
                        char* __restrict__ ws)
{
    int id = blockIdx.x * 256 + threadIdx.x;   // 48*4096 threads
    int lh = id >> 12, pos = id & 4095;
    int n = pos >> 6, k = pos & 63;
    float s = 0.f;
    if (n <= 49 && k <= 49) {
        const float* aq = (n < 49) ? &wq[((size_t)lh * 49 + n) * 49] : &bq[(size_t)lh * 49];
        const float* ak = (k < 49) ? &wk[((size_t)lh * 49 + k) * 49] : &bk[(size_t)lh * 49];
        for (int e2 = 0; e2 < 49; ++e2) s += aq[e2] * ak[e2];
        s *= (1.f / 7.f);
    }
    ((unsigned short*)(ws + cfg::OFF_WQ))[(size_t)lh * 4096 + pos] = to_bf16(s);
}

// V weights packed [out e 64][in f 64], in-slot 49 = bias (consumed by pack_wvo)
__global__ void pack_v(const float* __restrict__ wv, const float* __restrict__ bv,
                       char* __restrict__ ws)
{
    int id = blockIdx.x * 256 + threadIdx.x;   // 48*4096 threads
    int lh = id >> 12, pos = id & 4095;
    int n = pos >> 6, k = pos & 63;
    float v = 0.f;
    if (n < 49) {
        if (k < 49)       v = wv[((size_t)lh * 49 + k) * 49 + n];
        else if (k == 49) v = bv[lh * 49 + n];
    }
    ((unsigned short*)(ws + cfg::OFF_WV))[(size_t)lh * 4096 + pos] = to_bf16(v);
}

// fused Whoo[lh][d out][e in] = sum_o Wh[lh][e][o]*Wo[l][h*49+o][d]; slot e=49 = bh@Wo + bo/8
// fused Mf[d out][e in] = sum_o M1[e][o]*M2[o][d]; slot e=49 = b1@M2 + b2
__global__ void pack_fused(const float* __restrict__ wh, const float* __restrict__ bh,
                           const float* __restrict__ wo, const float* __restrict__ bo,
                           const float* __restrict__ m1, const float* __restrict__ m1b,
                           const float* __restrict__ m2, const float* __restrict__ m2b,
                           char* __restrict__ ws)
{
    int id = blockIdx.x * 256 + threadIdx.x;     // 48*4096 + 4096 threads
    if (id < 48 * 4096) {
        int lh = id >> 12, pos = id & 4095;
        int l = lh >> 3, h = lh & 7;
        int d = pos >> 6, e = pos & 63;
        float s = 0.f;
        if (d < 49) {
            if (e < 49) {
                for (int o = 0; o < 49; ++o)
                    s += wh[((size_t)lh * 49 + e) * 49 + o] * wo[((size_t)l * 392 + h * 49 + o) * 49 + d];
            } else if (e == 49) {
                for (int o = 0; o < 49; ++o)
                    s += bh[lh * 49 + o] * wo[((size_t)l * 392 + h * 49 + o) * 49 + d];
                s += bo[l * 49 + d] * 0.125f;
            }
        }
        ((unsigned short*)(ws + cfg::OFF_WHOO))[(size_t)lh * 4096 + d * 64 + e] = to_bf16(s);
        return;
    }
    id -= 48 * 4096;
    if (id < 4096) {
        int d = id >> 6, e = id & 63;
        float s = 0.f;
        if (d < 49) {
            if (e < 49) {
                for (int o = 0; o < 49; ++o) s += m1[e * 49 + o] * m2[o * 49 + d];
            } else if (e == 49) {
                for (int o = 0; o < 49; ++o) s += m1b[o] * m2[o * 49 + d];
                s += m2b[d];
            }
        }
        ((unsigned short*)(ws + cfg::OFF_MF))[d * 64 + e] = to_bf16(s);
    }
}

// Fused Wvo[lh][d out][f in] = sum_{e<49} Wv_aug[f][e] * Whoo_w[d][e];
// f=49 row += Whoo bias slot (exact: softmax rows sum to 1).
// Rows d>=49 are exact zeros (Whoo pad).
__global__ void pack_wvo(char* __restrict__ ws)
{
    int id = blockIdx.x * 256 + threadIdx.x;   // 48*4096 threads
    int lh = id >> 12, pos = id & 4095;
    int d = pos >> 6, f = pos & 63;
    const unsigned short* WVp = (const unsigned short*)(ws + cfg::OFF_WV) + (size_t)lh * 4096;
    const unsigned short* WH  = (const unsigned short*)(ws + cfg::OFF_WHOO) + (size_t)lh * 4096;
    float s = 0.f;
    for (int e = 0; e < 49; ++e)
        s += bf2f(WVp[e * 64 + f]) * bf2f(WH[d * 64 + e]);
    if (f == 49) s += bf2f(WH[d * 64 + 49]);
    ((unsigned short*)(ws + cfg::OFF_WK))[(size_t)lh * 4096 + d * 64 + f] = to_bf16(s);
}

__global__ void pack_rest(const float* __restrict__ f1w, const float* __restrict__ f1b,
                          const float* __restrict__ f2w, const float* __restrict__ f2b,
                          const float* __restrict__ ppw, const float* __restrict__ ppb,
                          const float* __restrict__ pos, char* __restrict__ ws)
{
    int id = blockIdx.x * 256 + threadIdx.x;
    if (id < 6 * 208 * 64) {                                    // FFN1: [l][n=208][k=64], k-slot49=bias
        int l = id / (208 * 64), rem = id % (208 * 64), n = rem / 64, k = rem % 64;
        float v = 0.f;
        if (n < 196) {
            if (k < 49)       v = f1w[((size_t)l * 49 + k) * 196 + n];
            else if (k == 49) v = f1b[l * 196 + n];
        }
        ((unsigned short*)(ws + cfg::OFF_F1))[id] = to_bf16(v);
        return;
    }
    id -= 6 * 208 * 64;
    if (id < 6 * 64 * 224) {                                    // FFN2: [l][n=64][k=224], k-slot196=bias
        int l = id / (64 * 224), rem = id % (64 * 224), n = rem / 224, k = rem % 224;
        float v = 0.f;
        if (n < 49) {
            if (k < 196)       v = f2w[((size_t)l * 196 + k) * 49 + n];
            else if (k == 196) v = f2b[l * 49 + n];
        }
        ((unsigned short*)(ws + cfg::OFF_F2))[id] = to_bf16(v);
        return;
    }
    id -= 6 * 64 * 224;
    if (id < 4096) {                                            // patch proj [n][k] (bias via POSB)
        int n = id >> 6, k = id & 63;
        ((unsigned short*)(ws + cfg::OFF_PP))[id] = to_bf16((n < 49 && k < 49) ? ppw[k * 49 + n] : 0.f);
        return;
    }
    id -= 4096;
    if (id < 1024) {                                            // posb[p][e] = pos + patch bias
        int p = id >> 6, e = id & 63;
        ((float*)(ws + cfg::OFF_POSB))[id] = (e < 49) ? pos[p * 49 + e] + ppb[e] : 0.f;
        return;
    }
    id -= 1024;
    if (id < 128) ((float*)(ws + cfg::OFF_ACC))[id] = 0.f;      // zero accumulator bins
}

// ---------------- main fused kernel ----------------
// FINAL (revert to round-8 best, 1141-1194 us): 2 independent waves/WG,
// 2 elements each, 9216B private LDS per wave, zero barriers, in-register
// U/P transposes (4-lane shfl), chunked FFN1->FFN2, all weights prefused
// (Wqk = WqWk^T/7, Wvo = Wv(WhWo), Mf = M1M2, biases in K-slot 49).
// Session evidence: time tracks the per-wave issue stream (algebraic fusion
// r3/r4: -18%/-17%); occupancy 12-45% and two prefetch schemes (r6 regs,
// r9 async-LDS) all null. Per-wave issue duty is pinned at ~27% by the
// tiny dependent granules (49-dim, 16-tok) — structural floor here.

__global__ __launch_bounds__(128, 2)
void vit_main(const float* __restrict__ x, const int* __restrict__ trg,
              const float* __restrict__ cw1, const float* __restrict__ cb1,
              const float* __restrict__ cw2, const float* __restrict__ cb2,
              char* __restrict__ ws)
{
    constexpr int S64 = 72;           // [16][64] tile stride (ushorts), 144B
    constexpr int VC  = 36;           // FFN chunk [16 tok][32+4] stride, 72B
    constexpr int TA = 0, TB = 1152, EL = 2304;
    __shared__ unsigned short smb[4 * EL];   // 18432 B

    const int tid  = threadIdx.x;
    const int wid  = tid >> 6;               // which independent wave
    const int lane = tid & 63;
    const int g = lane >> 4, c = lane & 15;
    const long e0 = (long)blockIdx.x * 4 + wid * 2;
    unsigned short* const sm = smb + wid * 2 * EL;   // per-wave private LDS
    const f32x4 FZ = {0.f, 0.f, 0.f, 0.f};

    // shfl source lanes for the 4-lane D->frag transpose
    const int src0 = ((( 2 * g )     & 3) << 4) | c;
    const int src1 = (((2 * g + 1) & 3) << 4) | c;
    const bool glo = (g < 2);

    const unsigned short* WQK = (const unsigned short*)(ws + cfg::OFF_WQ);
    const unsigned short* WVO = (const unsigned short*)(ws + cfg::OFF_WK);
    const unsigned short* F1 = (const unsigned short*)(ws + cfg::OFF_F1);
    const unsigned short* F2 = (const unsigned short*)(ws + cfg::OFF_F2);
    const unsigned short* MF = (const unsigned short*)(ws + cfg::OFF_MF);
    const unsigned short* PP = (const unsigned short*)(ws + cfg::OFF_PP);
    const float* POSB = (const float*)(ws + cfg::OFF_POSB);
    float* ACC = (float*)(ws + cfg::OFF_ACC);

    // ---- stage x -> TA ([tok][feat] bf16, feats>=49 zero)
    #pragma unroll
    for (int u = 0; u < 2; ++u) {
        const float* xb = x + (e0 + u) * 784;
        #pragma unroll
        for (int it = 0; it < 8; ++it) {
            int i = it * 64 + lane;
            int p = i >> 5, ee = (i & 31) * 2;
            float v0 = (ee < 49) ? xb[p * 49 + ee] : 0.f;
            float v1 = (ee + 1 < 49) ? xb[p * 49 + ee + 1] : 0.f;
            *reinterpret_cast<unsigned int*>(&sm[u * EL + TA + p * S64 + ee]) = pk2(v0, v1);
        }
    }

    // B-fragment loader from a [16][64] tile (rows = n/tok, cols = k contiguous)
    bfrag a_h[2][2];
    auto loadB = [&](int off, bfrag (&af)[2][2]) {
        #pragma unroll
        for (int u = 0; u < 2; ++u)
            #pragma unroll
            for (int kk = 0; kk < 2; ++kk)
                af[u][kk] = *(const bfrag*)&sm[u * EL + off + c * S64 + kk * 32 + g * 8];
    };
    loadB(TA, a_h);

    // ---- patch proj (transposed) + posb -> hreg  (lane: f=16mt+4g+r, tok=c)
    f32x4 hreg[2][4];
    #pragma unroll
    for (int mt = 0; mt < 4; ++mt) {
        f32x4 t0 = FZ, t1 = FZ;
        #pragma unroll
        for (int kk = 0; kk < 2; ++kk) {
            bfrag w = *(const bfrag*)&PP[(mt * 16 + c) * 64 + kk * 32 + g * 8];
            t0 = mfma32(w, a_h[0][kk], t0);
            t1 = mfma32(w, a_h[1][kk], t1);
        }
        f32x4 pb = *(const f32x4*)&POSB[c * 64 + mt * 16 + 4 * g];
        hreg[0][mt] = t0 + pb;
        hreg[1][mt] = t1 + pb;
    }

    // =================== layer loop ===================
    for (int l = 0; l < 6; ++l) {
        // stage h -> TA, set constant-1 slot at feat 49
        #pragma unroll
        for (int u = 0; u < 2; ++u)
            #pragma unroll
            for (int mt = 0; mt < 4; ++mt)
                store4(&sm[u * EL + TA + c * S64 + mt * 16 + 4 * g],
                       hreg[u][mt][0], hreg[u][mt][1], hreg[u][mt][2], hreg[u][mt][3]);
        if (lane < 32) sm[(lane >> 4) * EL + TA + (lane & 15) * S64 + 49] = 0x3F80;
        loadB(TA, a_h);

        f32x4 oacc[2][4];
        #pragma unroll
        for (int u = 0; u < 2; ++u)
            #pragma unroll
            for (int mt = 0; mt < 4; ++mt) oacc[u][mt] = FZ;

        // ---------- attention heads ----------
        for (int hh = 0; hh < 8; ++hh) {
            const int lh = l * 8 + hh;
            const unsigned short* wqk = WQK + (size_t)lh * 4096;
            const unsigned short* wvo = WVO + (size_t)lh * 4096;

            // T[k_tok][fq] -> TB (the one remaining LDS round trip per head)
            #pragma unroll
            for (int mt = 0; mt < 4; ++mt) {
                f32x4 t0 = FZ, t1 = FZ;
                #pragma unroll
                for (int kk = 0; kk < 2; ++kk) {
                    bfrag wf = *(const bfrag*)&wqk[(mt * 16 + c) * 64 + kk * 32 + g * 8];
                    t0 = mfma32(wf, a_h[0][kk], t0);
                    t1 = mfma32(wf, a_h[1][kk], t1);
                }
                store4(&sm[0 * EL + TB + c * S64 + mt * 16 + 4 * g], t0[0], t0[1], t0[2], t0[3]);
                store4(&sm[1 * EL + TB + c * S64 + mt * 16 + 4 * g], t1[0], t1[1], t1[2], t1[3]);
            }

            // S^T = T·h_aug^T, softmax -> P as in-register B-frag (no LDS)
            bfrag bp[2];
            #pragma unroll
            for (int u = 0; u < 2; ++u) {
                f32x4 sc = FZ;
                #pragma unroll
                for (int kk = 0; kk < 2; ++kk) {
                    bfrag akf = *(const bfrag*)&sm[u * EL + TB + c * S64 + kk * 32 + g * 8];
                    sc = mfma32(akf, a_h[u][kk], sc);
                }
                float s0 = sc[0], s1 = sc[1], s2 = sc[2], s3 = sc[3];
                float m = fmaxf(fmaxf(s0, s1), fmaxf(s2, s3));
                m = fmaxf(m, __shfl_xor(m, 16));
                m = fmaxf(m, __shfl_xor(m, 32));
                float p0 = __expf(s0 - m), p1 = __expf(s1 - m);
                float p2 = __expf(s2 - m), p3 = __expf(s3 - m);
                float t = p0 + p1 + p2 + p3;
                t += __shfl_xor(t, 16);
                t += __shfl_xor(t, 32);
                float inv = fastrcp(t);
                // P[q=c][k=4g+r] -> B-frag needs P[q=c][k=8g+j]
                unsigned int pka = pk2(p0 * inv, p1 * inv);
                unsigned int pkb = pk2(p2 * inv, p3 * inv);
                unsigned int b0 = (unsigned)__shfl((int)pka, src0);
                unsigned int b1 = (unsigned)__shfl((int)pkb, src0);
                unsigned int b2 = (unsigned)__shfl((int)pka, src1);
                unsigned int b3 = (unsigned)__shfl((int)pkb, src1);
                bp[u] = bf_from(glo ? b0 : 0u, glo ? b1 : 0u,
                                glo ? b2 : 0u, glo ? b3 : 0u);
            }

            // U = h_aug·Wvo per nt, transpose in-register, PV accumulate
            #pragma unroll
            for (int nt = 0; nt < 4; ++nt) {
                bfrag wvf0 = *(const bfrag*)&wvo[(nt * 16 + c) * 64 + 0 * 32 + g * 8];
                bfrag wvf1 = *(const bfrag*)&wvo[(nt * 16 + c) * 64 + 1 * 32 + g * 8];
                #pragma unroll
                for (int u = 0; u < 2; ++u) {
                    f32x4 v = FZ;
                    v = mfma32(a_h[u][0], wvf0, v);
                    v = mfma32(a_h[u][1], wvf1, v);
                    unsigned int va = pk2(v[0], v[1]);
                    unsigned int vb = pk2(v[2], v[3]);
                    unsigned int u0 = (unsigned)__shfl((int)va, src0);
                    unsigned int u1 = (unsigned)__shfl((int)vb, src0);
                    unsigned int u2 = (unsigned)__shfl((int)va, src1);
                    unsigned int u3 = (unsigned)__shfl((int)vb, src1);
                    bfrag uf = bf_from(glo ? u0 : 0u, glo ? u1 : 0u,
                                       glo ? u2 : 0u, glo ? u3 : 0u);
                    oacc[u][nt] = mfma32(uf, bp[u], oacc[u][nt]);
                }
            }
        } // heads

        // ---------- LN1: y = LN(h + attn_out) -> yreg, store y -> TA (+slot) ----------
        f32x4 yreg[2][4];
        {
            const float* ln1wp = (const float*)(ws + cfg::OFF_POSB + 4096);  // LN tables after POSB
            const float* ln1bp = ln1wp + 384;
            #pragma unroll
            for (int u = 0; u < 2; ++u) {
                float z[4][4];
                float s = 0.f, q2 = 0.f;
                #pragma unroll
                for (int mt = 0; mt < 4; ++mt)
                    #pragma unroll
                    for (int r = 0; r < 4; ++r) {
                        float zz = hreg[u][mt][r] + oacc[u][mt][r];
                        z[mt][r] = zz;
                        s += zz;
                        q2 += zz * zz;
                    }
                s += __shfl_xor(s, 16); s += __shfl_xor(s, 32);
                q2 += __shfl_xor(q2, 16); q2 += __shfl_xor(q2, 32);
                float mu = s * (1.f / 49.f);
                float var = q2 * (1.f / 49.f) - mu * mu;
                float rstd = rsqrtf(var + 1e-5f);
                #pragma unroll
                for (int mt = 0; mt < 4; ++mt) {
                    f32x4 lwv = *(const f32x4*)&ln1wp[l * 64 + mt * 16 + 4 * g];
                    f32x4 lbv = *(const f32x4*)&ln1bp[l * 64 + mt * 16 + 4 * g];
                    #pragma unroll
                    for (int r = 0; r < 4; ++r)
                        yreg[u][mt][r] = (z[mt][r] - mu) * rstd * lwv[r] + lbv[r];
                    store4(&sm[u * EL + TA + c * S64 + mt * 16 + 4 * g],
                           yreg[u][mt][0], yreg[u][mt][1], yreg[u][mt][2], yreg[u][mt][3]);
                }
            }
        }
        if (lane < 32) sm[(lane >> 4) * EL + TA + (lane & 15) * S64 + 49] = 0x3F80;

        // ---------- FFN1 -> FFN2 chunked (32 mid-feats/chunk through TB) ----------
        f32x4 zac[2][4];
        #pragma unroll
        for (int u = 0; u < 2; ++u)
            #pragma unroll
            for (int mt = 0; mt < 4; ++mt) zac[u][mt] = FZ;
        {
            bfrag ay[2][2];
            loadB(TA, ay);
            const unsigned short* F1l = F1 + (size_t)l * 208 * 64;
            const unsigned short* F2l = F2 + (size_t)l * 64 * 224;
            #pragma unroll
            for (int ci = 0; ci < 7; ++ci) {
                #pragma unroll
                for (int t = 0; t < 2; ++t) {
                    const int mtile = ci * 2 + t;
                    if (mtile < 13) {
                        f32x4 m0 = FZ, m1 = FZ;
                        #pragma unroll
                        for (int kk = 0; kk < 2; ++kk) {
                            bfrag wf = *(const bfrag*)&F1l[(mtile * 16 + c) * 64 + kk * 32 + g * 8];
                            m0 = mfma32(wf, ay[0][kk], m0);
                            m1 = mfma32(wf, ay[1][kk], m1);
                        }
                        store4(&sm[0 * EL + TB + c * VC + t * 16 + 4 * g],
                               gelu(m0[0]), gelu(m0[1]), gelu(m0[2]), gelu(m0[3]));
                        store4(&sm[1 * EL + TB + c * VC + t * 16 + 4 * g],
                               gelu(m1[0]), gelu(m1[1]), gelu(m1[2]), gelu(m1[3]));
                    } else {
                        // mtile 13: mid cols 208..223 = zeros (K-pad for FFN2 kk=6)
                        int u2 = lane >> 5, r5 = lane & 31, row = r5 >> 1, half = r5 & 1;
                        *(f32x4*)&sm[u2 * EL + TB + row * VC + 16 + half * 8] = FZ;
                    }
                }
                if (ci == 6) {
                    // constant-1 slot at mid col 196 -> chunk local col 4
                    if (lane < 32) sm[(lane >> 4) * EL + TB + (lane & 15) * VC + 4] = 0x3F80;
                }
                // FFN2 partial accumulate: kk = ci
                #pragma unroll
                for (int u = 0; u < 2; ++u) {
                    bfrag am = *(const bfrag*)&sm[u * EL + TB + c * VC + g * 8];
                    #pragma unroll
                    for (int mt = 0; mt < 4; ++mt) {
                        bfrag wf = *(const bfrag*)&F2l[(mt * 16 + c) * 224 + ci * 32 + g * 8];
                        zac[u][mt] = mfma32(wf, am, zac[u][mt]);
                    }
                }
            }
        }

        // ---------- residual + LN2 -> hreg (hn), store hn -> TA (+slot) ----------
        {
            const float* ln2wp = (const float*)(ws + cfg::OFF_POSB + 4096) + 768;
            const float* ln2bp = ln2wp + 384;
            #pragma unroll
            for (int u = 0; u < 2; ++u) {
                float z[4][4];
                float s = 0.f, q2 = 0.f;
                #pragma unroll
                for (int mt = 0; mt < 4; ++mt)
                    #pragma unroll
                    for (int r = 0; r < 4; ++r) {
                        float zz = yreg[u][mt][r] + zac[u][mt][r];
                        z[mt][r] = zz;
                        s += zz;
                        q2 += zz * zz;
                    }
                s += __shfl_xor(s, 16); s += __shfl_xor(s, 32);
                q2 += __shfl_xor(q2, 16); q2 += __shfl_xor(q2, 32);
                float mu = s * (1.f / 49.f);
                float var = q2 * (1.f / 49.f) - mu * mu;
                float rstd = rsqrtf(var + 1e-5f);
                #pragma unroll
                for (int mt = 0; mt < 4; ++mt) {
                    f32x4 lwv = *(const f32x4*)&ln2wp[l * 64 + mt * 16 + 4 * g];
                    f32x4 lbv = *(const f32x4*)&ln2bp[l * 64 + mt * 16 + 4 * g];
                    #pragma unroll
                    for (int r = 0; r < 4; ++r)
                        hreg[u][mt][r] = (z[mt][r] - mu) * rstd * lwv[r] + lbv[r];
                    store4(&sm[u * EL + TA + c * S64 + mt * 16 + 4 * g],
                           hreg[u][mt][0], hreg[u][mt][1], hreg[u][mt][2], hreg[u][mt][3]);
                }
            }
        }
        if (lane < 32) sm[(lane >> 4) * EL + TA + (lane & 15) * S64 + 49] = 0x3F80;

        // ---------- inter-block MLP (fused M1@M2, bias in slot) ----------
        {
            bfrag an[2][2];
            loadB(TA, an);
            #pragma unroll
            for (int mt = 0; mt < 4; ++mt) {
                f32x4 t0 = FZ, t1 = FZ;
                #pragma unroll
                for (int kk = 0; kk < 2; ++kk) {
                    bfrag wf = *(const bfrag*)&MF[(mt * 16 + c) * 64 + kk * 32 + g * 8];
                    t0 = mfma32(wf, an[0][kk], t0);
                    t1 = mfma32(wf, an[1][kk], t1);
                }
                hreg[0][mt] = t0;
                hreg[1][mt] = t1;
            }
        }
    } // layers

    // =================== pooling + classifier + loss (fp32, per wave) ===================
    float loss_blk = 0.f, corr_blk = 0.f;
    #pragma unroll
    for (int u = 0; u < 2; ++u)
        #pragma unroll
        for (int mt = 0; mt < 4; ++mt)
            store4(&sm[u * EL + TA + c * S64 + mt * 16 + 4 * g],
                   hreg[u][mt][0], hreg[u][mt][1], hreg[u][mt][2], hreg[u][mt][3]);

    for (int u = 0; u < 2; ++u) {
        float s = 0.f;
        #pragma unroll
        for (int p = 0; p < 16; ++p)
            s += (float)(*reinterpret_cast<const __bf16*>(&sm[u * EL + TA + p * S64 + lane]));
        float* pf = reinterpret_cast<float*>(&sm[u * EL + TB]);   // TB dead: f32 scratch
        pf[lane] = s * (1.f / 16.f);
        if (lane < 25) {
            float t = cb1[lane];
            for (int d2 = 0; d2 < 49; ++d2) t += pf[d2] * cw1[d2 * 25 + lane];
            pf[64 + lane] = t;
        }
        if (lane < 10) {
            float t2 = cb2[lane];
            for (int k2 = 0; k2 < 25; ++k2) t2 += pf[64 + k2] * cw2[k2 * 10 + lane];
            pf[96 + lane] = t2;
        }
        if (lane == 0) {
            float m = pf[96]; int am_ = 0;
            for (int j = 1; j < 10; ++j) if (pf[96 + j] > m) { m = pf[96 + j]; am_ = j; }
            float se = 0.f;
            for (int j = 0; j < 10; ++j) se += __expf(pf[96 + j] - m);
            float logZ = m + logf(se);
            int t = trg[e0 + u];
            loss_blk += logZ - pf[96 + t];
            corr_blk += (am_ == t) ? 1.f : 0.f;
        }
    }
    if (lane == 0) {
        int bin = (int)((blockIdx.x * 2 + wid) & 63);
        atomicAdd(&ACC[bin * 2 + 0], loss_blk);
        atomicAdd(&ACC[bin * 2 + 1], corr_blk);
    }
}

// pack LN params [6][64] x4 (w1,b1,w2,b2) after POSB
__global__ void pack_ln(const float* __restrict__ ln1w, const float* __restrict__ ln1b,
                        const float* __restrict__ ln2w, const float* __restrict__ ln2b,
                        char* __restrict__ ws)
{
    int id = blockIdx.x * 256 + threadIdx.x;     // 1536 threads
    if (id >= 1536) return;
    int which = id / 384, r = id % 384, l = r >> 6, f = r & 63;
    const float* s = (which == 0) ? ln1w : (which == 1) ? ln1b : (which == 2) ? ln2w : ln2b;
    float v = (f < 49) ? s[l * 49 + f] : 0.f;
    ((float*)(ws + cfg::OFF_POSB + 4096))[which * 384 + r] = v;
}

__global__ void finalize_k(const char* __restrict__ ws, float* __restrict__ out)
{
    const float* ACC = (const float*)(ws + cfg::OFF_ACC);
    int lane = threadIdx.x;
    float a = ACC[lane * 2 + 0];
    float b = ACC[lane * 2 + 1];
    for (int m = 1; m < 64; m <<= 1) {
        a += __shfl_xor(a, m);
        b += __shfl_xor(b, m);
    }
    if (lane == 0) {
        out[0] = a * (1.f / 16384.f);
        out[1] = b * (1.f / 16384.f);
    }
}

// ---------------- host launcher ----------------

extern "C" void kernel_launch(void* const* d_in, const int* in_sizes, int n_in,
                              void* d_out, int out_size, void* d_ws, size_t ws_size,
                              hipStream_t stream)
{
    const float* x    = (const float*)d_in[0];
    const int*   trg  = (const int*)  d_in[1];
    const float* ppw  = (const float*)d_in[2];
    const float* ppb  = (const float*)d_in[3];
    const float* pos  = (const float*)d_in[4];
    const float* wq   = (const float*)d_in[5];
    const float* bq   = (const float*)d_in[6];
    const float* wk   = (const float*)d_in[7];
    const float* bk   = (const float*)d_in[8];
    const float* wv   = (const float*)d_in[9];
    const float* bv   = (const float*)d_in[10];
    const float* wh   = (const float*)d_in[11];
    const float* bh   = (const float*)d_in[12];
    const float* wo   = (const float*)d_in[13];
    const float* bo   = (const float*)d_in[14];
    const float* ln1w = (const float*)d_in[15];
    const float* ln1b = (const float*)d_in[16];
    const float* ln2w = (const float*)d_in[17];
    const float* ln2b = (const float*)d_in[18];
    const float* f1w  = (const float*)d_in[19];
    const float* f1b  = (const float*)d_in[20];
    const float* f2w  = (const float*)d_in[21];
    const float* f2b  = (const float*)d_in[22];
    const float* m1w  = (const float*)d_in[23];
    const float* m1b  = (const float*)d_in[24];
    const float* m2w  = (const float*)d_in[25];
    const float* m2b  = (const float*)d_in[26];
    const float* cw1  = (const float*)d_in[27];
    const float* cb1  = (const float*)d_in[28];
    const float* cw2  = (const float*)d_in[29];
    const float* cb2  = (const float*)d_in[30];
    char* ws = (char*)d_ws;

    pack_qk<<<768, 256, 0, stream>>>(wq, bq, wk, bk, ws);
    pack_v<<<768, 256, 0, stream>>>(wv, bv, ws);
    pack_fused<<<784, 256, 0, stream>>>(wh, bh, wo, bo, m1w, m1b, m2w, m2b, ws);
    pack_wvo<<<768, 256, 0, stream>>>(ws);
    pack_rest<<<669, 256, 0, stream>>>(f1w, f1b, f2w, f2b, ppw, ppb, pos, ws);
    pack_ln<<<6, 256, 0, stream>>>(ln1w, ln1b, ln2w, ln2b, ws);
    vit_main<<<16384 / 4, 128, 0, stream>>>(x, trg, cw1, cb1, cw2, cb2, ws);
    finalize_k<<<1, 64, 0, stream>>>(ws, (float*)d_out);
}